// Round 8
// baseline (148.027 us; speedup 1.0000x reference)
//
#include <hip/hip_runtime.h>

#define LN_EPS 1e-5f

typedef _Float16 hv2 __attribute__((ext_vector_type(2)));

#define PIN_F(x) asm volatile("" : "+v"(x))
#define PIN_H2(x)                                             \
    do {                                                      \
        unsigned _u = __builtin_bit_cast(unsigned, x);        \
        asm volatile("" : "+v"(_u));                          \
        x = __builtin_bit_cast(hv2, _u);                      \
    } while (0)

__device__ __forceinline__ float fast_rcp(float x) {
    return __builtin_amdgcn_rcpf(x);
}

__device__ __forceinline__ hv2 cvt2(float a, float b) {
    return __builtin_bit_cast(hv2, __builtin_amdgcn_cvt_pkrtz(a, b));   // v_cvt_pkrtz_f16_f32
}

__device__ __forceinline__ hv2 pkfma(hv2 a, hv2 b, hv2 c) {
    return __builtin_elementwise_fma(a, b, c);                          // v_pk_fma_f16
}

// paired silu: one v_rcp for two elements. exp-arg clamped so d0*d1 stays finite.
__device__ __forceinline__ void silu_pair(float a0, float a1, float& s0, float& s1) {
    float t0 = __expf(fminf(-a0, 80.0f));
    float t1 = __expf(fminf(-a1, 80.0f));
    float d0 = 1.0f + t0, d1 = 1.0f + t1;
    float rp = fast_rcp(d0 * d1);
    s0 = a0 * (d1 * rp);
    s1 = a1 * (d0 * rp);
}

// paired tanh: tanh(x) = 2/(1+exp(-2x)) - 1
__device__ __forceinline__ void tanh_pair(float x0, float x1, float& r0, float& r1) {
    float t0 = __expf(fminf(-2.0f * x0, 80.0f));
    float t1 = __expf(fminf(-2.0f * x1, 80.0f));
    float d0 = 1.0f + t0, d1 = 1.0f + t1;
    float rp = fast_rcp(d0 * d1);
    r0 = fmaf(2.0f, d1 * rp, -1.0f);
    r1 = fmaf(2.0f, d0 * rp, -1.0f);
}

__device__ __forceinline__ float softplus_f(float x) {
    float e = __expf(-fabsf(x));
    return fmaxf(x, 0.0f) + __logf(1.0f + e);
}

// ---- d_ws layout (hv2 = neuron-pair packed, [K][N/2]) ----
// gw1p  [16][4]  @ 0     (64)
// gw2p  [8]      @ 64    (8)    pair = (logit0, logit1) per k
// gb1p  [4]      @ 72    (4)
// e1w1p [16][12] @ 76    (192)
// e1w2p [24][8]  @ 268   (192)
// e1b1p [12]     @ 460
// e1b2p [8]      @ 472
// e2w1p [16][12] @ 480   (192)
// e2w2p [24][8]  @ 672   (192)
// e2b1p [12]     @ 864
// e2b2p [8]      @ 876
// twp   [16][8]  @ 884   (128)
// tbp   [8]      @ 1012  -> total 1020

__global__ void pack_weights(const float* __restrict__ gw1, const float* __restrict__ gb1,
                             const float* __restrict__ gw2,
                             const float* __restrict__ e1w1, const float* __restrict__ e1b1,
                             const float* __restrict__ e1w2, const float* __restrict__ e1b2,
                             const float* __restrict__ e2w1, const float* __restrict__ e2b1,
                             const float* __restrict__ e2w2, const float* __restrict__ e2b2,
                             const float* __restrict__ tw, const float* __restrict__ tb,
                             hv2* __restrict__ ws) {
    int t = blockIdx.x * blockDim.x + threadIdx.x;
    if (t < 64) {                                     // gw1 (16,8)
        int k = t >> 2, j2 = t & 3;
        ws[t] = cvt2(gw1[k * 8 + 2 * j2], gw1[k * 8 + 2 * j2 + 1]);
    } else if (t < 72) {                              // gw2 (8,2): pair = both logits
        int k = t - 64;
        ws[t] = cvt2(gw2[k * 2 + 0], gw2[k * 2 + 1]);
    } else if (t < 76) {                              // gb1 (8)
        int j2 = t - 72;
        ws[t] = cvt2(gb1[2 * j2], gb1[2 * j2 + 1]);
    } else if (t < 268) {                             // e1w1 (16,24)
        int e = t - 76, k = e / 12, j2 = e % 12;
        ws[t] = cvt2(e1w1[k * 24 + 2 * j2], e1w1[k * 24 + 2 * j2 + 1]);
    } else if (t < 460) {                             // e1w2 (24,16)
        int e = t - 268, k = e >> 3, j2 = e & 7;
        ws[t] = cvt2(e1w2[k * 16 + 2 * j2], e1w2[k * 16 + 2 * j2 + 1]);
    } else if (t < 472) {                             // e1b1 (24)
        int j2 = t - 460;
        ws[t] = cvt2(e1b1[2 * j2], e1b1[2 * j2 + 1]);
    } else if (t < 480) {                             // e1b2 (16)
        int j2 = t - 472;
        ws[t] = cvt2(e1b2[2 * j2], e1b2[2 * j2 + 1]);
    } else if (t < 672) {                             // e2w1
        int e = t - 480, k = e / 12, j2 = e % 12;
        ws[t] = cvt2(e2w1[k * 24 + 2 * j2], e2w1[k * 24 + 2 * j2 + 1]);
    } else if (t < 864) {                             // e2w2
        int e = t - 672, k = e >> 3, j2 = e & 7;
        ws[t] = cvt2(e2w2[k * 16 + 2 * j2], e2w2[k * 16 + 2 * j2 + 1]);
    } else if (t < 876) {                             // e2b1
        int j2 = t - 864;
        ws[t] = cvt2(e2b1[2 * j2], e2b1[2 * j2 + 1]);
    } else if (t < 884) {                             // e2b2
        int j2 = t - 876;
        ws[t] = cvt2(e2b2[2 * j2], e2b2[2 * j2 + 1]);
    } else if (t < 1012) {                            // tw (16,16)
        int e = t - 884, k = e >> 3, j2 = e & 7;
        ws[t] = cvt2(tw[k * 16 + 2 * j2], tw[k * 16 + 2 * j2 + 1]);
    } else if (t < 1020) {                            // tb (16)
        int j2 = t - 1012;
        ws[t] = cvt2(tb[2 * j2], tb[2 * j2 + 1]);
    }
}

// One expert. xh[k] = splat(x_k) as hv2. acc (+)= scale * silu(h@w2+b2), fp32.
template <bool FIRST>
__device__ __forceinline__ void expert_pk16(const hv2 xh[16],
                                            const hv2* __restrict__ w1p,   // [16][12]
                                            const hv2* __restrict__ b1p,   // [12]
                                            const hv2* __restrict__ w2p,   // [24][8]
                                            const hv2* __restrict__ b2p,   // [8]
                                            const float* __restrict__ g,
                                            const float* __restrict__ bn,
                                            float scale, float* __restrict__ acc) {
    // ---- layer 1: hh[12] (packed pairs), fp16 accum ----
    hv2 hh[12];
#pragma unroll
    for (int j2 = 0; j2 < 12; ++j2) hh[j2] = b1p[j2];
#pragma unroll
    for (int k = 0; k < 16; ++k)
#pragma unroll
        for (int j2 = 0; j2 < 12; ++j2)
            hh[j2] = pkfma(xh[k], w1p[k * 12 + j2], hh[j2]);
#pragma unroll
    for (int j2 = 0; j2 < 12; ++j2) PIN_H2(hh[j2]);   // forbid remat of L1 chains

    // ---- LN stats ----
    float E = 0.0f, E2 = 0.0f;
#pragma unroll
    for (int j2 = 0; j2 < 12; ++j2) {
        float a = (float)hh[j2].x, b = (float)hh[j2].y;
        E += a + b;
        E2 = fmaf(a, a, fmaf(b, b, E2));
    }
    float mu = E * (1.0f / 24.0f);
    float var = fmaf(E2, 1.0f / 24.0f, -mu * mu);
    float rstd = rsqrtf(var + LN_EPS);

    // ---- norm + silu (paired rcp), repack into hh ----
#pragma unroll
    for (int j2 = 0; j2 < 12; ++j2) {
        float a = (float)hh[j2].x, b = (float)hh[j2].y;
        float n0 = fmaf((a - mu) * rstd, g[2 * j2], bn[2 * j2]);
        float n1 = fmaf((b - mu) * rstd, g[2 * j2 + 1], bn[2 * j2 + 1]);
        float s0, s1;
        silu_pair(n0, n1, s0, s1);
        hh[j2] = cvt2(s0, s1);
    }
#pragma unroll
    for (int j2 = 0; j2 < 12; ++j2) PIN_H2(hh[j2]);   // forbid remat of LN/silu chains

    // ---- layer 2: ov[8] packed pairs; splats unpacked on the fly ----
    hv2 ov[8];
#pragma unroll
    for (int j2 = 0; j2 < 8; ++j2) ov[j2] = b2p[j2];
#pragma unroll
    for (int k2 = 0; k2 < 12; ++k2) {
        hv2 lo = {hh[k2].x, hh[k2].x};
        hv2 hi = {hh[k2].y, hh[k2].y};
#pragma unroll
        for (int j2 = 0; j2 < 8; ++j2)
            ov[j2] = pkfma(lo, w2p[(2 * k2) * 8 + j2], ov[j2]);
#pragma unroll
        for (int j2 = 0; j2 < 8; ++j2)
            ov[j2] = pkfma(hi, w2p[(2 * k2 + 1) * 8 + j2], ov[j2]);
    }

#pragma unroll
    for (int j2 = 0; j2 < 8; ++j2) {
        float s0, s1;
        silu_pair((float)ov[j2].x, (float)ov[j2].y, s0, s1);
        if (FIRST) {
            acc[2 * j2 + 0] = scale * s0;
            acc[2 * j2 + 1] = scale * s1;
        } else {
            acc[2 * j2 + 0] = fmaf(scale, s0, acc[2 * j2 + 0]);
            acc[2 * j2 + 1] = fmaf(scale, s1, acc[2 * j2 + 1]);
        }
    }
}

__global__ __launch_bounds__(256) void moe_fused_kernel(
    const float* __restrict__ x,
    const hv2* __restrict__ ws,
    const float* __restrict__ gb2,
    const float* __restrict__ e1g, const float* __restrict__ e1bn,
    const float* __restrict__ e2g, const float* __restrict__ e2bn,
    const float* __restrict__ sw, const float* __restrict__ sb,
    const float* __restrict__ hw, const float* __restrict__ hb,
    float* __restrict__ out, int nrows) {
    int row = blockIdx.x * blockDim.x + threadIdx.x;
    if (row >= nrows) return;

    const hv2* gw1p  = ws;
    const hv2* gw2p  = ws + 64;
    const hv2* gb1p  = ws + 72;
    const hv2* e1w1p = ws + 76;
    const hv2* e1w2p = ws + 268;
    const hv2* e1b1p = ws + 460;
    const hv2* e1b2p = ws + 472;
    const hv2* e2w1p = ws + 480;
    const hv2* e2w2p = ws + 672;
    const hv2* e2b1p = ws + 864;
    const hv2* e2b2p = ws + 876;
    const hv2* twp   = ws + 884;
    const hv2* tbp   = ws + 1012;

    // ---- load x row; build splat-pair regs ----
    float xv[16];
    const float4* xr = reinterpret_cast<const float4*>(x + (size_t)row * 16);
#pragma unroll
    for (int i = 0; i < 4; ++i) {
        float4 v = xr[i];
        xv[4 * i + 0] = v.x;
        xv[4 * i + 1] = v.y;
        xv[4 * i + 2] = v.z;
        xv[4 * i + 3] = v.w;
    }
    hv2 xh[16];
#pragma unroll
    for (int k = 0; k < 16; ++k) xh[k] = cvt2(xv[k], xv[k]);
#pragma unroll
    for (int k = 0; k < 16; ++k) PIN_H2(xh[k]);       // materialize once, no remat

    // ---- gate ----
    hv2 ga[4];
#pragma unroll
    for (int j2 = 0; j2 < 4; ++j2) ga[j2] = gb1p[j2];
#pragma unroll
    for (int k = 0; k < 16; ++k)
#pragma unroll
        for (int j2 = 0; j2 < 4; ++j2)
            ga[j2] = pkfma(xh[k], gw1p[k * 4 + j2], ga[j2]);
    hv2 gl = cvt2(gb2[0], gb2[1]);
#pragma unroll
    for (int j2 = 0; j2 < 4; ++j2) {
        float t0, t1;
        tanh_pair((float)ga[j2].x, (float)ga[j2].y, t0, t1);
        hv2 s0 = cvt2(t0, t0), s1 = cvt2(t1, t1);
        gl = pkfma(s0, gw2p[2 * j2 + 0], gl);
        gl = pkfma(s1, gw2p[2 * j2 + 1], gl);
    }
    float w0 = fast_rcp(1.0f + __expf((float)gl.y - (float)gl.x));   // sigmoid(l0-l1)
    float w1v = 1.0f - w0;

    // ---- experts (sequential; one expert's state live) ----
    float h[16];
    expert_pk16<true >(xh, e1w1p, e1b1p, e1w2p, e1b2p, e1g, e1bn, w0,  h);
    expert_pk16<false>(xh, e2w1p, e2b1p, e2w2p, e2b2p, e2g, e2bn, w1v, h);
#pragma unroll
    for (int j = 0; j < 16; ++j) PIN_F(h[j]);         // keep combined h materialized

    // ---- trunk: t = silu(h@tw + tb) ----
    hv2 tt[8];
#pragma unroll
    for (int j2 = 0; j2 < 8; ++j2) tt[j2] = tbp[j2];
#pragma unroll
    for (int k = 0; k < 16; ++k) {
        hv2 hs = cvt2(h[k], h[k]);
#pragma unroll
        for (int j2 = 0; j2 < 8; ++j2)
            tt[j2] = pkfma(hs, twp[k * 8 + j2], tt[j2]);
    }
    float t[16];
#pragma unroll
    for (int j2 = 0; j2 < 8; ++j2) {
        float s0, s1;
        silu_pair((float)tt[j2].x, (float)tt[j2].y, s0, s1);
        t[2 * j2 + 0] = s0;
        t[2 * j2 + 1] = s1;
    }

    // ---- heads (fp32) ----
    float strain = sb[0], hs0 = hb[0], hs1 = hb[1];
#pragma unroll
    for (int k = 0; k < 16; ++k) {
        strain = fmaf(t[k], sw[k], strain);
        hs0 = fmaf(t[k], hw[2 * k + 0], hs0);
        hs1 = fmaf(t[k], hw[2 * k + 1], hs1);
    }
    float gap = softplus_f(hs1);

    size_t o = (size_t)row * 3;
    out[o + 0] = strain;
    out[o + 1] = hs0;        // tensile_raw
    out[o + 2] = hs0 - gap;  // yield_strength
}

extern "C" void kernel_launch(void* const* d_in, const int* in_sizes, int n_in,
                              void* d_out, int out_size, void* d_ws, size_t ws_size,
                              hipStream_t stream) {
    const float* x    = (const float*)d_in[0];
    const float* gw1  = (const float*)d_in[1];
    const float* gb1  = (const float*)d_in[2];
    const float* gw2  = (const float*)d_in[3];
    const float* gb2  = (const float*)d_in[4];
    const float* e1w1 = (const float*)d_in[5];
    const float* e1b1 = (const float*)d_in[6];
    const float* e1g  = (const float*)d_in[7];
    const float* e1bn = (const float*)d_in[8];
    const float* e1w2 = (const float*)d_in[9];
    const float* e1b2 = (const float*)d_in[10];
    const float* e2w1 = (const float*)d_in[11];
    const float* e2b1 = (const float*)d_in[12];
    const float* e2g  = (const float*)d_in[13];
    const float* e2bn = (const float*)d_in[14];
    const float* e2w2 = (const float*)d_in[15];
    const float* e2b2 = (const float*)d_in[16];
    const float* tw   = (const float*)d_in[17];
    const float* tb   = (const float*)d_in[18];
    const float* sw   = (const float*)d_in[19];
    const float* sb   = (const float*)d_in[20];
    const float* hw   = (const float*)d_in[21];
    const float* hb   = (const float*)d_in[22];
    float* out = (float*)d_out;
    hv2* ws = (hv2*)d_ws;

    pack_weights<<<4, 256, 0, stream>>>(gw1, gb1, gw2, e1w1, e1b1, e1w2, e1b2,
                                        e2w1, e2b1, e2w2, e2b2, tw, tb, ws);

    int nrows = in_sizes[0] / 16;
    int block = 256;
    int grid = (nrows + block - 1) / block;
    moe_fused_kernel<<<grid, block, 0, stream>>>(
        x, ws, gb2, e1g, e1bn, e2g, e2bn, sw, sb, hw, hb, out, nrows);
}

// Round 10
// 122.140 us; speedup vs baseline: 1.2119x; 1.2119x over previous
//
#include <hip/hip_runtime.h>

#define LN_EPS 1e-5f

typedef _Float16 f16x4 __attribute__((ext_vector_type(4)));
typedef float f32x4 __attribute__((ext_vector_type(4)));
typedef unsigned int u32;
typedef u32 u32x2 __attribute__((ext_vector_type(2)));

#if defined(__HIP_DEVICE_COMPILE__)
#  if __has_builtin(__builtin_amdgcn_mfma_f32_16x16x16f16)
#    define MFMA16(a, b, c) __builtin_amdgcn_mfma_f32_16x16x16f16(a, b, c, 0, 0, 0)
#  elif __has_builtin(__builtin_amdgcn_mfma_f32_16x16x16_f16)
#    define MFMA16(a, b, c) __builtin_amdgcn_mfma_f32_16x16x16_f16(a, b, c, 0, 0, 0)
#  else
#    error "no 16x16x16 f16 mfma builtin on device"
#  endif
#else
#  define MFMA16(a, b, c) (c)   /* host pass: parse-only dummy, never executed */
#endif

__device__ __forceinline__ float fast_rcp(float x) { return __builtin_amdgcn_rcpf(x); }

__device__ __forceinline__ u32 pk2(float a, float b) {
    return __builtin_bit_cast(u32, __builtin_amdgcn_cvt_pkrtz(a, b));
}
__device__ __forceinline__ f16x4 mk4(float a, float b, float c, float d) {
    u32x2 t = {pk2(a, b), pk2(c, d)};
    return __builtin_bit_cast(f16x4, t);
}

__device__ __forceinline__ void silu_pair(float a0, float a1, float& s0, float& s1) {
    float t0 = __expf(fminf(-a0, 80.0f));
    float t1 = __expf(fminf(-a1, 80.0f));
    float d0 = 1.0f + t0, d1 = 1.0f + t1;
    float rp = fast_rcp(d0 * d1);
    s0 = a0 * (d1 * rp);
    s1 = a1 * (d0 * rp);
}
__device__ __forceinline__ void tanh_pair(float x0, float x1, float& r0, float& r1) {
    float t0 = __expf(fminf(-2.0f * x0, 80.0f));
    float t1 = __expf(fminf(-2.0f * x1, 80.0f));
    float d0 = 1.0f + t0, d1 = 1.0f + t1;
    float rp = fast_rcp(d0 * d1);
    r0 = fmaf(2.0f, d1 * rp, -1.0f);
    r1 = fmaf(2.0f, d0 * rp, -1.0f);
}
__device__ __forceinline__ float softplus_f(float x) {
    float e = __expf(-fabsf(x));
    return fmaxf(x, 0.0f) + __logf(1.0f + e);
}

// ======================= d_ws layout (dword units) =======================
// [0, 1536):   A fragments, 12 mfma x 64 lanes x 2 dwords (f16x4 each)
//              mfma idx: 0:g1 1:g2 2:e1L1a 3:e1L1b 4:e1L2a 5:e1L2b
//                        6:e2L1a 7:e2L1b 8:e2L2a 9:e2L2b 10:trunk 11:heads
// [1536,4096): bias C-in fragments, 10 x 64 x 4 f32
//              0:g1 1:g2 2:e1L1a 3:e1L1b 4:e1L2 5:e2L1a 6:e2L1b 7:e2L2 8:trunk 9:heads
// [4096,6144): LN norm fragments, (expert*4+w) x 64 x 4 f32; w: 0:gC1 1:bnC1 2:gC2 3:bnC2
// =========================================================================

__device__ __forceinline__ float aval(int m, int row, int k,
                                      const float* gw1, const float* gw2,
                                      const float* e1w1, const float* e1w2,
                                      const float* e2w1, const float* e2w2,
                                      const float* tw, const float* sw, const float* hw) {
    switch (m) {
        case 0:  return (row < 8) ? gw1[k * 8 + row] : 0.0f;                     // g1: (16,8)
        case 1:  return (row < 2 && k < 8) ? gw2[k * 2 + row] : 0.0f;            // g2: (8,2)
        case 2:  return e1w1[k * 24 + row];                                      // e1 L1 feats 0-15
        case 3:  return (row < 8) ? e1w1[k * 24 + 16 + row] : 0.0f;              // e1 L1 feats 16-23
        case 4:  return e1w2[k * 16 + row];                                      // e1 L2 k 0-15
        case 5:  return (k < 8) ? e1w2[(16 + k) * 16 + row] : 0.0f;              // e1 L2 k 16-23
        case 6:  return e2w1[k * 24 + row];
        case 7:  return (row < 8) ? e2w1[k * 24 + 16 + row] : 0.0f;
        case 8:  return e2w2[k * 16 + row];
        case 9:  return (k < 8) ? e2w2[(16 + k) * 16 + row] : 0.0f;
        case 10: return tw[k * 16 + row];                                        // trunk (16,16)
        default:                                                                 // heads
            if (row == 0) return sw[k];
            if (row == 1) return hw[2 * k + 0];
            if (row == 2) return hw[2 * k + 1];
            return 0.0f;
    }
}

__device__ __forceinline__ float bval(int bf, int row,
                                      const float* gb1, const float* gb2,
                                      const float* e1b1, const float* e1b2,
                                      const float* e2b1, const float* e2b2,
                                      const float* tb, const float* sb, const float* hb) {
    switch (bf) {
        case 0:  return (row < 8) ? gb1[row] : 0.0f;
        case 1:  return (row < 2) ? gb2[row] : 0.0f;
        case 2:  return e1b1[row];
        case 3:  return (row < 8) ? e1b1[16 + row] : 0.0f;
        case 4:  return e1b2[row];
        case 5:  return e2b1[row];
        case 6:  return (row < 8) ? e2b1[16 + row] : 0.0f;
        case 7:  return e2b2[row];
        case 8:  return tb[row];
        default:
            if (row == 0) return sb[0];
            if (row == 1) return hb[0];
            if (row == 2) return hb[1];
            return 0.0f;
    }
}

__global__ void pack_frags(const float* __restrict__ gw1, const float* __restrict__ gb1,
                           const float* __restrict__ gw2, const float* __restrict__ gb2,
                           const float* __restrict__ e1w1, const float* __restrict__ e1b1,
                           const float* __restrict__ e1g, const float* __restrict__ e1bn,
                           const float* __restrict__ e1w2, const float* __restrict__ e1b2,
                           const float* __restrict__ e2w1, const float* __restrict__ e2b1,
                           const float* __restrict__ e2g, const float* __restrict__ e2bn,
                           const float* __restrict__ e2w2, const float* __restrict__ e2b2,
                           const float* __restrict__ tw, const float* __restrict__ tb,
                           const float* __restrict__ sw, const float* __restrict__ sb,
                           const float* __restrict__ hw, const float* __restrict__ hb,
                           u32* __restrict__ ws) {
    int t = blockIdx.x * blockDim.x + threadIdx.x;
    if (t < 1536) {
        // A fragments: one u32 (2 f16) per thread
        int m = t >> 7, rem = t & 127, lane = rem >> 1, d = rem & 1;
        int row = lane & 15, k0 = (lane >> 4) * 4 + 2 * d;
        float v0 = aval(m, row, k0,     gw1, gw2, e1w1, e1w2, e2w1, e2w2, tw, sw, hw);
        float v1 = aval(m, row, k0 + 1, gw1, gw2, e1w1, e1w2, e2w1, e2w2, tw, sw, hw);
        ws[t] = pk2(v0, v1);
    } else if (t < 4096) {
        int f = t - 1536;
        int bf = f >> 8, rem = f & 255, lane = rem >> 2, r = rem & 3;
        int row = (lane >> 4) * 4 + r;
        float v = bval(bf, row, gb1, gb2, e1b1, e1b2, e2b1, e2b2, tb, sb, hb);
        ((float*)ws)[t] = v;
    } else if (t < 6144) {
        int f = t - 4096;
        int nf = f >> 8, rem = f & 255, lane = rem >> 2, r = rem & 3;
        int e = nf >> 2, w = nf & 3, g_ = lane >> 4;
        const float* ge = e ? e2g : e1g;
        const float* bne = e ? e2bn : e1bn;
        float v;
        if (w < 2) {
            int feat = g_ * 4 + r;
            v = (w == 0) ? ge[feat] : bne[feat];
        } else {
            int feat = 16 + g_ * 4 + r;
            v = (g_ < 2) ? ((w == 2) ? ge[feat] : bne[feat]) : 0.0f;
        }
        ((float*)ws)[t] = v;
    }
}

// One expert: C-in carries biases; LN+silu glue; h (+)= scale * silu(L2)
template <bool FIRST>
__device__ __forceinline__ void expert_mfma(f16x4 A1a, f16x4 A1b, f16x4 A2a, f16x4 A2b,
                                            f32x4 b1a, f32x4 b1b, f32x4 b2,
                                            f32x4 gc1, f32x4 bc1, f32x4 gc2, f32x4 bc2,
                                            f16x4 Bx, float scale, f32x4& h) {
    f32x4 C1 = MFMA16(A1a, Bx, b1a);
    f32x4 C2 = MFMA16(A1b, Bx, b1b);
    float E = (C1[0] + C1[1]) + (C1[2] + C1[3]) + (C2[0] + C2[1]) + (C2[2] + C2[3]);
    float E2 = 0.0f;
#pragma unroll
    for (int i = 0; i < 4; ++i) E2 = fmaf(C1[i], C1[i], E2);
#pragma unroll
    for (int i = 0; i < 4; ++i) E2 = fmaf(C2[i], C2[i], E2);
    E  += __shfl_xor(E, 16);  E  += __shfl_xor(E, 32);
    E2 += __shfl_xor(E2, 16); E2 += __shfl_xor(E2, 32);
    float mu = E * (1.0f / 24.0f);
    float var = fmaf(E2, 1.0f / 24.0f, -mu * mu);
    float rstd = rsqrtf(var + LN_EPS);
    float n[8], sv[8];
#pragma unroll
    for (int i = 0; i < 4; ++i) n[i]     = fmaf((C1[i] - mu) * rstd, gc1[i], bc1[i]);
#pragma unroll
    for (int i = 0; i < 4; ++i) n[4 + i] = fmaf((C2[i] - mu) * rstd, gc2[i], bc2[i]);
    silu_pair(n[0], n[1], sv[0], sv[1]);
    silu_pair(n[2], n[3], sv[2], sv[3]);
    silu_pair(n[4], n[5], sv[4], sv[5]);
    silu_pair(n[6], n[7], sv[6], sv[7]);
    f16x4 B1 = mk4(sv[0], sv[1], sv[2], sv[3]);
    f16x4 B2 = mk4(sv[4], sv[5], sv[6], sv[7]);
    f32x4 O = MFMA16(A2a, B1, b2);
    O = MFMA16(A2b, B2, O);
    float so0, so1, so2, so3;
    silu_pair(O[0], O[1], so0, so1);
    silu_pair(O[2], O[3], so2, so3);
    if (FIRST) {
        h[0] = scale * so0; h[1] = scale * so1; h[2] = scale * so2; h[3] = scale * so3;
    } else {
        h[0] = fmaf(scale, so0, h[0]); h[1] = fmaf(scale, so1, h[1]);
        h[2] = fmaf(scale, so2, h[2]); h[3] = fmaf(scale, so3, h[3]);
    }
}

__global__ __launch_bounds__(256) void moe_mfma_kernel(const float* __restrict__ x,
                                                       const u32* __restrict__ ws,
                                                       float* __restrict__ out, int nrows) {
    const f16x4* Afr = (const f16x4*)ws;                 // [12*64]
    const float* wsf = (const float*)ws;
    const f32x4* Bfr = (const f32x4*)(wsf + 1536);       // [10*64]
    const f32x4* Nfr = (const f32x4*)(wsf + 4096);       // [8*64]

    int lane = threadIdx.x & 63;
    int g = lane >> 4, s = lane & 15;
    int wid = (blockIdx.x * blockDim.x + threadIdx.x) >> 6;
    int nw = (gridDim.x * blockDim.x) >> 6;

    // ---- preload all fragments to registers ----
    f16x4 Ag1 = Afr[0 * 64 + lane], Ag2 = Afr[1 * 64 + lane];
    f16x4 A1a = Afr[2 * 64 + lane], A1b = Afr[3 * 64 + lane];
    f16x4 A2a = Afr[4 * 64 + lane], A2b = Afr[5 * 64 + lane];
    f16x4 A3a = Afr[6 * 64 + lane], A3b = Afr[7 * 64 + lane];
    f16x4 A4a = Afr[8 * 64 + lane], A4b = Afr[9 * 64 + lane];
    f16x4 Atr = Afr[10 * 64 + lane], Ahd = Afr[11 * 64 + lane];
    f32x4 Bg1 = Bfr[0 * 64 + lane], Bg2 = Bfr[1 * 64 + lane];
    f32x4 Be1a = Bfr[2 * 64 + lane], Be1b = Bfr[3 * 64 + lane], Be1o = Bfr[4 * 64 + lane];
    f32x4 Be2a = Bfr[5 * 64 + lane], Be2b = Bfr[6 * 64 + lane], Be2o = Bfr[7 * 64 + lane];
    f32x4 Btr = Bfr[8 * 64 + lane], Bhd = Bfr[9 * 64 + lane];
    f32x4 G1c1 = Nfr[0 * 64 + lane], B1c1 = Nfr[1 * 64 + lane];
    f32x4 G1c2 = Nfr[2 * 64 + lane], B1c2 = Nfr[3 * 64 + lane];
    f32x4 G2c1 = Nfr[4 * 64 + lane], B2c1 = Nfr[5 * 64 + lane];
    f32x4 G2c2 = Nfr[6 * 64 + lane], B2c2 = Nfr[7 * 64 + lane];

    int ntiles = (nrows + 15) >> 4;
    for (int tile = wid; tile < ntiles; tile += nw) {
        int r0 = tile * 16 + s;
        int rc = r0 < nrows ? r0 : nrows - 1;
        const f32x4 xv = *(const f32x4*)(x + (size_t)rc * 16 + g * 4);
        f16x4 Bx = mk4(xv[0], xv[1], xv[2], xv[3]);

        // ---- gate ----
        f32x4 Cg = MFMA16(Ag1, Bx, Bg1);
        float t0, t1, t2, t3;
        tanh_pair(Cg[0], Cg[1], t0, t1);
        tanh_pair(Cg[2], Cg[3], t2, t3);
        f16x4 Bt = mk4(t0, t1, t2, t3);
        f32x4 Cl = MFMA16(Ag2, Bt, Bg2);
        float l0 = __shfl(Cl[0], s, 64);   // broadcast logit rows (group 0) to all lanes
        float l1 = __shfl(Cl[1], s, 64);
        float w0 = fast_rcp(1.0f + __expf(l1 - l0));   // sigmoid(l0 - l1)
        float w1 = 1.0f - w0;

        // ---- experts ----
        f32x4 h;
        expert_mfma<true >(A1a, A1b, A2a, A2b, Be1a, Be1b, Be1o, G1c1, B1c1, G1c2, B1c2, Bx, w0, h);
        expert_mfma<false>(A3a, A3b, A4a, A4b, Be2a, Be2b, Be2o, G2c1, B2c1, G2c2, B2c2, Bx, w1, h);

        // ---- trunk ----
        f16x4 Bh = mk4(h[0], h[1], h[2], h[3]);
        f32x4 Ct = MFMA16(Atr, Bh, Btr);
        float u0, u1, u2, u3;
        silu_pair(Ct[0], Ct[1], u0, u1);
        silu_pair(Ct[2], Ct[3], u2, u3);
        f16x4 Bu = mk4(u0, u1, u2, u3);

        // ---- heads ----
        f32x4 Ch = MFMA16(Ahd, Bu, Bhd);
        if (g == 0 && r0 < nrows) {
            float strain = Ch[0];
            float tens = Ch[1];
            float yld = tens - softplus_f(Ch[2]);
            size_t o = (size_t)r0 * 3;
            out[o + 0] = strain;
            out[o + 1] = tens;
            out[o + 2] = yld;
        }
    }
}

extern "C" void kernel_launch(void* const* d_in, const int* in_sizes, int n_in,
                              void* d_out, int out_size, void* d_ws, size_t ws_size,
                              hipStream_t stream) {
    const float* x    = (const float*)d_in[0];
    const float* gw1  = (const float*)d_in[1];
    const float* gb1  = (const float*)d_in[2];
    const float* gw2  = (const float*)d_in[3];
    const float* gb2  = (const float*)d_in[4];
    const float* e1w1 = (const float*)d_in[5];
    const float* e1b1 = (const float*)d_in[6];
    const float* e1g  = (const float*)d_in[7];
    const float* e1bn = (const float*)d_in[8];
    const float* e1w2 = (const float*)d_in[9];
    const float* e1b2 = (const float*)d_in[10];
    const float* e2w1 = (const float*)d_in[11];
    const float* e2b1 = (const float*)d_in[12];
    const float* e2g  = (const float*)d_in[13];
    const float* e2bn = (const float*)d_in[14];
    const float* e2w2 = (const float*)d_in[15];
    const float* e2b2 = (const float*)d_in[16];
    const float* tw   = (const float*)d_in[17];
    const float* tb   = (const float*)d_in[18];
    const float* sw   = (const float*)d_in[19];
    const float* sb   = (const float*)d_in[20];
    const float* hw   = (const float*)d_in[21];
    const float* hb   = (const float*)d_in[22];
    float* out = (float*)d_out;
    u32* ws = (u32*)d_ws;

    pack_frags<<<24, 256, 0, stream>>>(gw1, gb1, gw2, gb2,
                                       e1w1, e1b1, e1g, e1bn, e1w2, e1b2,
                                       e2w1, e2b1, e2g, e2bn, e2w2, e2b2,
                                       tw, tb, sw, sb, hw, hb, ws);

    int nrows = in_sizes[0] / 16;
    moe_mfma_kernel<<<2048, 256, 0, stream>>>(x, ws, out, nrows);
}